// Round 1
// baseline (210.654 us; speedup 1.0000x reference)
//
#include <hip/hip_runtime.h>
#include <math.h>

#define LAMBDA_DAG 0.5f

// -------- Kernel 1: probs (transposed via LDS tile, coalesced both sides)
//          + BCE per-block partials + zero the kernel-2 atomic accumulators ----
__global__ void __launch_bounds__(256) k_probs_bce(
        const float* __restrict__ logits,
        const float* __restrict__ labels,
        float* __restrict__ pT,        // [C*B] transposed probs
        float* __restrict__ bce_part,  // [gridDim.x]
        float* __restrict__ per_term,  // [C]  (zeroed here)
        float* __restrict__ npar,      // [C]  (zeroed here)
        int B, int C) {
    // Zero atomic accumulators for kernel 2 (workspace is poisoned between runs;
    // kernel-boundary on the stream orders these writes before kernel 2 reads).
    for (int i = blockIdx.x * blockDim.x + threadIdx.x; i < C;
         i += gridDim.x * blockDim.x) {
        per_term[i] = 0.f;
        npar[i] = 0.f;
    }

    __shared__ float tile[64][65];  // +1 pad: 2-way LDS bank aliasing only (free)
    __shared__ float sred[256];

    const int c0 = blockIdx.x * 64;
    float acc = 0.f;

    if (B <= 64 && (B & 3) == 0) {
        // --- tiled path (B=64): coalesced loads, LDS transpose, float4 stores ---
        const int lc = threadIdx.x & 63;       // column within tile
        const int c  = c0 + lc;
        const bool valid = (c < C);
        for (int b = threadIdx.x >> 6; b < B; b += (blockDim.x >> 6)) {
            float l = 0.f, y = 0.f;
            if (valid) {
                l = logits[(size_t)b * C + c];   // lanes 0..63 -> 256B contiguous
                y = labels[(size_t)b * C + c];
                // logaddexp(0,l) = max(l,0) + log1p(exp(-|l|))
                acc += fmaxf(l, 0.f) + log1pf(expf(-fabsf(l))) - l * y;
            }
            tile[lc][b] = 1.f / (1.f + expf(-l));
        }
        __syncthreads();
        const int B4  = B >> 2;
        const int tot = 64 * B4;
        for (int t = threadIdx.x; t < tot; t += blockDim.x) {
            const int row = t / B4;
            const int q   = t - row * B4;
            const int c2  = c0 + row;
            if (c2 < C) {
                float4 v;
                v.x = tile[row][q * 4 + 0];
                v.y = tile[row][q * 4 + 1];
                v.z = tile[row][q * 4 + 2];
                v.w = tile[row][q * 4 + 3];
                *(float4*)(pT + (size_t)c2 * B + q * 4) = v;  // contiguous per row
            }
        }
    } else {
        // --- generic fallback: scattered transposed store (correctness path) ---
        const int N = B * C;
        for (int idx = blockIdx.x * blockDim.x + threadIdx.x; idx < N;
             idx += gridDim.x * blockDim.x) {
            float l = logits[idx];
            float y = labels[idx];
            acc += fmaxf(l, 0.f) + log1pf(expf(-fabsf(l))) - l * y;
            float p = 1.f / (1.f + expf(-l));
            int b = idx / C;
            int cc = idx - b * C;
            pT[(size_t)cc * B + b] = p;
        }
    }

    sred[threadIdx.x] = acc;
    __syncthreads();
    for (int s = blockDim.x >> 1; s > 0; s >>= 1) {
        if (threadIdx.x < s) sred[threadIdx.x] += sred[threadIdx.x + s];
        __syncthreads();
    }
    if (threadIdx.x == 0) bce_part[blockIdx.x] = sred[0];
}

// -------- Kernel 2: flat coalesced float4 scan of the dag matrix ------------
// The job is streaming 100 MB to find ~0.08% nonzeros; per-hit compute is rare.
// Grid-stride float4, low VGPR -> high occupancy -> HBM-BW-bound (m13 shape).
__global__ void __launch_bounds__(256) k_dag_scan(
        const float* __restrict__ dag,   // [C*C], row i = parents of i
        const float* __restrict__ pT,    // [C*B] transposed probs (L2-resident)
        float* __restrict__ per_term,    // [C]  atomic accum
        float* __restrict__ npar,        // [C]  atomic accum
        int B, int C) {
    const size_t N  = (size_t)C * (size_t)C;
    const size_t N4 = N >> 2;
    const float4* dag4 = (const float4*)dag;
    const size_t stride = (size_t)gridDim.x * blockDim.x;
    const int B4 = B >> 2;

    for (size_t q = (size_t)blockIdx.x * blockDim.x + threadIdx.x; q < N4;
         q += stride) {
        float4 d = dag4[q];
        if (d.x > 0.f || d.y > 0.f || d.z > 0.f || d.w > 0.f) {
            const size_t base = q << 2;
            float dv[4] = {d.x, d.y, d.z, d.w};
#pragma unroll
            for (int k = 0; k < 4; ++k) {
                if (dv[k] > 0.f) {
                    const size_t e = base + (size_t)k;
                    const int i = (int)(e / (size_t)C);   // rare: ~20K hits total
                    const int j = (int)(e - (size_t)i * (size_t)C);
                    const float4* pi4 = (const float4*)(pT + (size_t)i * B);
                    const float4* pj4 = (const float4*)(pT + (size_t)j * B);
                    float s = 0.f;
                    for (int t = 0; t < B4; ++t) {
                        float4 a = pi4[t], b = pj4[t];
                        float d0 = fmaxf(a.x - b.x, 0.f);
                        float d1 = fmaxf(a.y - b.y, 0.f);
                        float d2 = fmaxf(a.z - b.z, 0.f);
                        float d3 = fmaxf(a.w - b.w, 0.f);
                        s += d0 * d0 + d1 * d1 + d2 * d2 + d3 * d3;
                    }
                    for (int b = B4 << 2; b < B; ++b) {
                        float diff = fmaxf(pT[(size_t)i * B + b] -
                                           pT[(size_t)j * B + b], 0.f);
                        s += diff * diff;
                    }
                    atomicAdd(&per_term[i], s);
                    atomicAdd(&npar[i], 1.f);
                }
            }
        }
    }
    // scalar tail for N % 4 (C=5000 -> none, stay general)
    for (size_t e = (N4 << 2) + (size_t)blockIdx.x * blockDim.x + threadIdx.x;
         e < N; e += stride) {
        if (dag[e] > 0.f) {
            const int i = (int)(e / (size_t)C);
            const int j = (int)(e - (size_t)i * (size_t)C);
            float s = 0.f;
            for (int b = 0; b < B; ++b) {
                float diff = fmaxf(pT[(size_t)i * B + b] -
                                   pT[(size_t)j * B + b], 0.f);
                s += diff * diff;
            }
            atomicAdd(&per_term[i], s);
            atomicAdd(&npar[i], 1.f);
        }
    }
}

// -------- Kernel 3: final scalar reduction ----------------------------------
__global__ void k_final(const float* __restrict__ per_term,
                        const float* __restrict__ npar,
                        const float* __restrict__ bce_part, int nb,
                        float* __restrict__ out, int B, int C) {
    float bs = 0.f, ps = 0.f, es = 0.f;
    for (int k = threadIdx.x; k < nb; k += blockDim.x) bs += bce_part[k];
    for (int i = threadIdx.x; i < C; i += blockDim.x) {
        float np = npar[i];
        es += np;
        if (np > 0.f) ps += per_term[i] / ((float)B * np);
    }
    __shared__ float s1[256], s2[256], s3[256];
    s1[threadIdx.x] = bs;
    s2[threadIdx.x] = ps;
    s3[threadIdx.x] = es;
    __syncthreads();
    for (int s = blockDim.x >> 1; s > 0; s >>= 1) {
        if (threadIdx.x < s) {
            s1[threadIdx.x] += s1[threadIdx.x + s];
            s2[threadIdx.x] += s2[threadIdx.x + s];
            s3[threadIdx.x] += s3[threadIdx.x + s];
        }
        __syncthreads();
    }
    if (threadIdx.x == 0) {
        float penalty = (s3[0] > 0.f) ? (s2[0] / s3[0]) : 0.f;
        out[0] = s1[0] / (float)(B * C) + LAMBDA_DAG * penalty;
    }
}

extern "C" void kernel_launch(void* const* d_in, const int* in_sizes, int n_in,
                              void* d_out, int out_size, void* d_ws, size_t ws_size,
                              hipStream_t stream) {
    const float* logits = (const float*)d_in[0];
    const float* labels = (const float*)d_in[1];
    const float* dag    = (const float*)d_in[2];
    float* out = (float*)d_out;

    const int C = (int)(sqrt((double)in_sizes[2]) + 0.5);
    const int B = in_sizes[0] / C;

    float* ws       = (float*)d_ws;
    float* pT       = ws;                          // C*B floats
    float* per_term = pT + (size_t)C * B;          // C floats
    float* nparw    = per_term + C;                // C floats
    float* bce_part = nparw + C;                   // gridA floats

    const int gridA = (C + 63) / 64;               // 79 tiles at C=5000

    k_probs_bce<<<gridA, 256, 0, stream>>>(logits, labels, pT, bce_part,
                                           per_term, nparw, B, C);

    const size_t N4 = ((size_t)C * (size_t)C) >> 2;
    size_t needB = (N4 + 255) / 256;
    const int gridB = (int)(needB < 2048 ? needB : 2048);
    k_dag_scan<<<gridB, 256, 0, stream>>>(dag, pT, per_term, nparw, B, C);

    k_final<<<1, 256, 0, stream>>>(per_term, nparw, bce_part, gridA, out, B, C);
}

// Round 2
// 190.548 us; speedup vs baseline: 1.1055x; 1.1055x over previous
//
#include <hip/hip_runtime.h>
#include <math.h>

#define LAMBDA_DAG 0.5f

// -------- Kernel 1: probs (transposed via LDS tile, coalesced both sides)
//          + BCE per-block partials + zero the kernel-2 atomic accumulators ----
// Grid: (ceil(C/64), ceil(B/16)) blocks of 256 threads.
__global__ void __launch_bounds__(256) k_probs_bce(
        const float* __restrict__ logits,
        const float* __restrict__ labels,
        float* __restrict__ pT,        // [C*B] transposed probs
        float* __restrict__ bce_part,  // [gridDim.x*gridDim.y]
        float* __restrict__ per_term,  // [C]  (zeroed here)
        float* __restrict__ npar,      // [C]  (zeroed here)
        int B, int C) {
    const int nb  = gridDim.x * gridDim.y;
    const int bid = blockIdx.y * gridDim.x + blockIdx.x;

    // Zero atomic accumulators for kernel 2 (workspace is poisoned between
    // runs; kernel boundary on the stream orders these before kernel 2).
    for (int i = bid * blockDim.x + threadIdx.x; i < C; i += nb * blockDim.x) {
        per_term[i] = 0.f;
        npar[i] = 0.f;
    }

    __shared__ float tile[64][17];  // pad: stride-17 across lanes = conflict-free
    __shared__ float sred[256];

    const int c0 = blockIdx.x * 64;
    const int b0 = blockIdx.y * 16;
    const int rows = (B - b0 < 16) ? (B - b0) : 16;

    const int lc = threadIdx.x & 63;  // column within tile
    const int c  = c0 + lc;
    const bool valid = (c < C);
    float acc = 0.f;

    if (rows > 0) {
        for (int r = threadIdx.x >> 6; r < rows; r += (blockDim.x >> 6)) {
            const int b = b0 + r;
            float l = 0.f, y = 0.f;
            if (valid) {
                l = logits[(size_t)b * C + c];  // lanes 0..63 -> 256B contiguous
                y = labels[(size_t)b * C + c];
                // logaddexp(0,l) = max(l,0) + log1p(exp(-|l|))
                acc += fmaxf(l, 0.f) + log1pf(expf(-fabsf(l))) - l * y;
            }
            tile[lc][r] = 1.f / (1.f + expf(-l));
        }
    }
    __syncthreads();

    if (rows > 0) {
        if ((rows & 3) == 0) {
            const int r4  = rows >> 2;
            const int tot = 64 * r4;
            for (int t = threadIdx.x; t < tot; t += blockDim.x) {
                const int row = t / r4;
                const int q   = t - row * r4;
                const int c2  = c0 + row;
                if (c2 < C) {
                    float4 v;
                    v.x = tile[row][q * 4 + 0];
                    v.y = tile[row][q * 4 + 1];
                    v.z = tile[row][q * 4 + 2];
                    v.w = tile[row][q * 4 + 3];
                    *(float4*)(pT + (size_t)c2 * B + b0 + q * 4) = v;
                }
            }
        } else {
            const int tot = 64 * rows;
            for (int t = threadIdx.x; t < tot; t += blockDim.x) {
                const int row = t / rows;
                const int r   = t - row * rows;
                const int c2  = c0 + row;
                if (c2 < C) pT[(size_t)c2 * B + b0 + r] = tile[row][r];
            }
        }
    }

    sred[threadIdx.x] = acc;
    __syncthreads();
    for (int s = blockDim.x >> 1; s > 0; s >>= 1) {
        if (threadIdx.x < s) sred[threadIdx.x] += sred[threadIdx.x + s];
        __syncthreads();
    }
    if (threadIdx.x == 0) bce_part[bid] = sred[0];
}

// -------- Kernel 2: flat scan of the dag, 8 independent float4 loads/thread --
// Round-1 lesson: MLP=1 grid-stride is latency-bound (70us at 10% HBM).
// Batch 8 loads up front -> 64 loads in flight per SIMD -> BW-bound.
#define SCAN_U 8
__global__ void __launch_bounds__(256) k_dag_scan(
        const float* __restrict__ dag,   // [C*C], row i = parents of i
        const float* __restrict__ pT,    // [C*B] transposed probs (L2-resident)
        float* __restrict__ per_term,    // [C]  atomic accum
        float* __restrict__ npar,        // [C]  atomic accum
        int B, int C) {
    const int N  = C * C;                 // 25M fits int32
    const int N4 = N >> 2;
    const float4* dag4 = (const float4*)dag;
    const int tileN   = blockDim.x * SCAN_U;          // 2048 float4/block-iter
    const int gstride = gridDim.x * tileN;
    const int B4 = B >> 2;
    const bool b4ok = ((B & 3) == 0);

    for (int base = blockIdx.x * tileN + threadIdx.x; base < N4;
         base += gstride) {
        float4 d[SCAN_U];
        // 8 independent loads issued back-to-back (the MLP fix)
#pragma unroll
        for (int u = 0; u < SCAN_U; ++u) {
            const int idx = base + u * 256;
            if (idx < N4) d[u] = dag4[idx];
            else          d[u] = make_float4(0.f, 0.f, 0.f, 0.f);
        }
        // dag entries are exactly 0.0f or 1.0f -> bitwise OR is a valid
        // any-nonzero test; one rarely-taken branch for all 32 floats.
        unsigned any = 0u;
#pragma unroll
        for (int u = 0; u < SCAN_U; ++u) {
            any |= __float_as_uint(d[u].x) | __float_as_uint(d[u].y) |
                   __float_as_uint(d[u].z) | __float_as_uint(d[u].w);
        }
        if (any != 0u) {
#pragma unroll
            for (int u = 0; u < SCAN_U; ++u) {
                const float dv[4] = {d[u].x, d[u].y, d[u].z, d[u].w};
#pragma unroll
                for (int k = 0; k < 4; ++k) {
                    if (dv[k] > 0.f) {
                        const int e = (base + u * 256) * 4 + k;
                        const int i = e / C;            // rare: ~20K hits total
                        const int j = e - i * C;
                        float s = 0.f;
                        if (b4ok) {
                            const float4* pi4 = (const float4*)(pT + (size_t)i * B);
                            const float4* pj4 = (const float4*)(pT + (size_t)j * B);
#pragma unroll 2
                            for (int t = 0; t < B4; ++t) {
                                float4 a = pi4[t], b = pj4[t];
                                float d0 = fmaxf(a.x - b.x, 0.f);
                                float d1 = fmaxf(a.y - b.y, 0.f);
                                float d2 = fmaxf(a.z - b.z, 0.f);
                                float d3 = fmaxf(a.w - b.w, 0.f);
                                s += d0 * d0 + d1 * d1 + d2 * d2 + d3 * d3;
                            }
                        } else {
                            for (int b = 0; b < B; ++b) {
                                float diff = fmaxf(pT[(size_t)i * B + b] -
                                                   pT[(size_t)j * B + b], 0.f);
                                s += diff * diff;
                            }
                        }
                        atomicAdd(&per_term[i], s);
                        atomicAdd(&npar[i], 1.f);
                    }
                }
            }
        }
    }
}

// -------- Kernel 3: final scalar reduction ----------------------------------
__global__ void k_final(const float* __restrict__ per_term,
                        const float* __restrict__ npar,
                        const float* __restrict__ bce_part, int nb,
                        float* __restrict__ out, int B, int C) {
    float bs = 0.f, ps = 0.f, es = 0.f;
    for (int k = threadIdx.x; k < nb; k += blockDim.x) bs += bce_part[k];
    for (int i = threadIdx.x; i < C; i += blockDim.x) {
        float np = npar[i];
        es += np;
        if (np > 0.f) ps += per_term[i] / ((float)B * np);
    }
    __shared__ float s1[256], s2[256], s3[256];
    s1[threadIdx.x] = bs;
    s2[threadIdx.x] = ps;
    s3[threadIdx.x] = es;
    __syncthreads();
    for (int s = blockDim.x >> 1; s > 0; s >>= 1) {
        if (threadIdx.x < s) {
            s1[threadIdx.x] += s1[threadIdx.x + s];
            s2[threadIdx.x] += s2[threadIdx.x + s];
            s3[threadIdx.x] += s3[threadIdx.x + s];
        }
        __syncthreads();
    }
    if (threadIdx.x == 0) {
        float penalty = (s3[0] > 0.f) ? (s2[0] / s3[0]) : 0.f;
        out[0] = s1[0] / (float)(B * C) + LAMBDA_DAG * penalty;
    }
}

extern "C" void kernel_launch(void* const* d_in, const int* in_sizes, int n_in,
                              void* d_out, int out_size, void* d_ws, size_t ws_size,
                              hipStream_t stream) {
    const float* logits = (const float*)d_in[0];
    const float* labels = (const float*)d_in[1];
    const float* dag    = (const float*)d_in[2];
    float* out = (float*)d_out;

    const int C = (int)(sqrt((double)in_sizes[2]) + 0.5);
    const int B = in_sizes[0] / C;

    float* ws       = (float*)d_ws;
    float* pT       = ws;                          // C*B floats
    float* per_term = pT + (size_t)C * B;          // C floats
    float* nparw    = per_term + C;                // C floats
    float* bce_part = nparw + C;                   // gridAx*gridAy floats

    const int gridAx = (C + 63) / 64;              // 79 col-tiles at C=5000
    const int gridAy = (B + 15) / 16;              // 4 batch-slices at B=64
    dim3 gA(gridAx, gridAy);
    k_probs_bce<<<gA, 256, 0, stream>>>(logits, labels, pT, bce_part,
                                        per_term, nparw, B, C);

    const int N4 = (C * C) >> 2;
    const int tileN = 256 * SCAN_U;                // 2048
    const int gridB = (N4 + tileN - 1) / tileN;    // 3052 at C=5000 (single pass)
    k_dag_scan<<<gridB, 256, 0, stream>>>(dag, pT, per_term, nparw, B, C);

    k_final<<<1, 256, 0, stream>>>(per_term, nparw, bce_part, gridAx * gridAy,
                                   out, B, C);
}